// Round 6
// baseline (316.657 us; speedup 1.0000x reference)
//
#include <hip/hip_runtime.h>
#include <hip/hip_bf16.h>

typedef __attribute__((ext_vector_type(8))) short short8;  // 8 bf16 (4 VGPRs)
typedef __attribute__((ext_vector_type(4))) short short4v;
typedef __attribute__((ext_vector_type(4))) float f32x4;
typedef __attribute__((ext_vector_type(2))) float f32x2;

#define INF_BITS 0x7F800000u

// ---------------------------------------------------------------------------
// prep: fp32 -> bf16, exact fp32 row norms, init min arrays. 16 lanes per row,
// float4 loads / short4 (8B) stores.
// ---------------------------------------------------------------------------
__global__ __launch_bounds__(256) void ahd_prep(
    const float* __restrict__ s1, const float* __restrict__ s2,
    __hip_bfloat16* __restrict__ abf, __hip_bfloat16* __restrict__ bbf,
    float* __restrict__ x2, float* __restrict__ y2,
    unsigned int* __restrict__ rmin, unsigned int* __restrict__ cmin,
    int N, int M)
{
    const int t   = blockIdx.x * 256 + threadIdx.x;
    const int row = t >> 4;
    const int sub = t & 15;

    if (t < N)          rmin[t]     = INF_BITS;
    else if (t < N + M) cmin[t - N] = INF_BITS;

    const float* src; __hip_bfloat16* dst; float* nrm; int r;
    if (row < N)            { src = s1; dst = abf; nrm = x2; r = row; }
    else if (row < N + M)   { src = s2; dst = bbf; nrm = y2; r = row - N; }
    else return;

    const float4 v = *(const float4*)&src[(size_t)r * 64 + sub * 4];
    __hip_bfloat16 h0 = __float2bfloat16(v.x), h1 = __float2bfloat16(v.y);
    __hip_bfloat16 h2 = __float2bfloat16(v.z), h3 = __float2bfloat16(v.w);
    short4v sv = { *(short*)&h0, *(short*)&h1, *(short*)&h2, *(short*)&h3 };
    *(short4v*)&dst[(size_t)r * 64 + sub * 4] = sv;

    float ss = v.x * v.x + v.y * v.y + v.z * v.z + v.w * v.w;
    ss += __shfl_xor(ss, 1);
    ss += __shfl_xor(ss, 2);
    ss += __shfl_xor(ss, 4);
    ss += __shfl_xor(ss, 8);
    if (sub == 0) nrm[r] = ss;
}

// ---------------------------------------------------------------------------
// fused distance-GEMM + row/col min.
// Block: 64 rows x 1024 cols, 4 waves; wave = 64x32 per col-tile (4m x 2n of
// 16x16x32). A staged to LDS once; B prefetched into a PER-WAVE PRIVATE LDS
// double-buffer via global_load_lds + hand-counted s_waitcnt vmcnt(4) -- no
// barriers, no prefetch registers (round-5 lesson: bnxt/bcur regs blew the
// (256,3) cap -> 300MB scratch spill). y^2 preloaded to regs so the loop's
// vmcnt count is exact. Epilogue: pk_fma on adjacent acc pairs + min3 trees.
// ---------------------------------------------------------------------------
__global__ __launch_bounds__(256, 3) void ahd_gemm(
    const __hip_bfloat16* __restrict__ abf, const __hip_bfloat16* __restrict__ bbf,
    const float* __restrict__ x2, const float* __restrict__ y2,
    unsigned int* __restrict__ rmin, unsigned int* __restrict__ cmin,
    int NRB, int nwg)
{
    __shared__ __attribute__((aligned(128))) char ldsA[8192];
    __shared__ __attribute__((aligned(128))) char ldsB[32768]; // [wave][2][4096]
    __shared__ __attribute__((aligned(16)))  float ldsX[64];
    __shared__ float        colbuf[1024];
    __shared__ unsigned int lrow[64];

    const int tid  = threadIdx.x;
    const int lane = tid & 63;
    const int w    = tid >> 6;
    const int lr   = lane & 15, lh = lane >> 4;

    // XCD-bijective swizzle (nwg % 8 == 0)
    const int bid = blockIdx.x;
    const int swz = (bid & 7) * (nwg >> 3) + (bid >> 3);
    const int brow  = (swz % NRB) * 64;
    const int bcol0 = (swz / NRB) * 1024;

    // per-lane swizzled staging offset (involution: bits[6:4] ^= bits[9:7])
    const int soff = (lane * 16) ^ ((lane & 0x38) << 1);

    // ---- stage A tile (8 KB) once; linear LDS dest, swizzled source
    const char* aT = (const char*)abf + (size_t)brow * 128;
    #pragma unroll
    for (int it = 0; it < 2; ++it) {
        const int dst = w * 1024 + it * 4096;
        const int o   = dst + lane * 16;
        const int so  = o ^ ((o >> 3) & 0x70);
        __builtin_amdgcn_global_load_lds(
            (const __attribute__((address_space(1))) void*)(aT + so),
            (__attribute__((address_space(3))) void*)(ldsA + dst), 16, 0, 0);
    }

    // ---- stage B tile 0 into this wave's private buf0
    const char* bsrc0 = (const char*)bbf + (size_t)(bcol0 + w * 32) * 128;
    char* ldsBw = ldsB + w * 8192;
    #pragma unroll
    for (int it = 0; it < 4; ++it)
        __builtin_amdgcn_global_load_lds(
            (const __attribute__((address_space(1))) void*)(bsrc0 + it * 1024 + soff),
            (__attribute__((address_space(3))) void*)(ldsBw + it * 1024), 16, 0, 0);

    // ---- preload x^2 (regs), y^2 for all 8 tiles (regs), init flush buffers
    f32x4 xq[4];
    #pragma unroll
    for (int m = 0; m < 4; ++m)
        xq[m] = *(const f32x4*)&x2[brow + m * 16 + lh * 4];
    const int col0 = bcol0 + w * 32 + lr;
    float yr0[8], yr1[8];
    #pragma unroll
    for (int ct = 0; ct < 8; ++ct) {
        yr0[ct] = y2[col0 + ct * 128];
        yr1[ct] = y2[col0 + ct * 128 + 16];
    }
    if (tid < 64) { ldsX[tid] = x2[brow + tid]; lrow[tid] = INF_BITS; }

    __syncthreads();   // drains A + B0 staging; the ONLY barrier before flush

    // ---- cache A fragments in registers (reused for all 8 col-tiles)
    short8 afr[2][4];
    #pragma unroll
    for (int ks = 0; ks < 2; ++ks)
        #pragma unroll
        for (int m = 0; m < 4; ++m) {
            int o = (m * 16 + lr) * 128 + ks * 64 + lh * 16;
            o ^= (o >> 3) & 0x70;
            afr[ks][m] = *(const short8*)(ldsA + o);
        }

    // precomputed swizzled B-frag offsets (loop-invariant; buf bit is >=4096)
    int off_bq[4];
    #pragma unroll
    for (int q = 0; q < 4; ++q) {
        int o = lr * 128 + lh * 16 + (q & 1) * 2048 + (q >> 1) * 64; // n=q&1,ks=q>>1
        off_bq[q] = o ^ ((o >> 3) & 0x70);
    }

    float rowm[4][4];
    #pragma unroll
    for (int m = 0; m < 4; ++m)
        #pragma unroll
        for (int j = 0; j < 4; ++j) rowm[m][j] = 1e30f;

    for (int ct = 0; ct < 8; ++ct) {
        // ---- issue prefetch of tile ct+1 into the other private buffer
        if (ct < 7) {
            const char* bt = bsrc0 + (size_t)(ct + 1) * 16384;
            char* db = ldsBw + ((ct + 1) & 1) * 4096;
            #pragma unroll
            for (int it = 0; it < 4; ++it)
                __builtin_amdgcn_global_load_lds(
                    (const __attribute__((address_space(1))) void*)(bt + it * 1024 + soff),
                    (__attribute__((address_space(3))) void*)(db + it * 1024), 16, 0, 0);
        }
        __builtin_amdgcn_sched_barrier(0);
        if (ct < 7) asm volatile("s_waitcnt vmcnt(4)" ::: "memory");
        else        asm volatile("s_waitcnt vmcnt(0)" ::: "memory");
        __builtin_amdgcn_sched_barrier(0);

        // ---- read this tile's B frags from the private buffer
        const char* bb = ldsBw + (ct & 1) * 4096;
        short8 bq[4];
        #pragma unroll
        for (int q = 0; q < 4; ++q)
            bq[q] = *(const short8*)(bb + off_bq[q]);

        // ---- MFMA: 2 ksteps x (4m x 2n); acc init folded into first MFMA
        f32x4 acc[4][2];
        #pragma unroll
        for (int ks = 0; ks < 2; ++ks)
            #pragma unroll
            for (int m = 0; m < 4; ++m)
                #pragma unroll
                for (int n = 0; n < 2; ++n) {
                    f32x4 c = (ks == 0) ? (f32x4){0.f, 0.f, 0.f, 0.f} : acc[m][n];
                    acc[m][n] = __builtin_amdgcn_mfma_f32_16x16x32_bf16(
                                    afr[ks][m], bq[ks * 2 + n], c, 0, 0, 0);
                }

        // ---- epilogue: pk_fma over adjacent j-pairs, v_min3-shaped trees
        const f32x2 mm2 = {-2.f, -2.f};
        const f32x2 yy0 = {yr0[ct], yr0[ct]};
        const f32x2 yy1 = {yr1[ct], yr1[ct]};
        float colm0 = 1e30f, colm1 = 1e30f;
        #pragma unroll
        for (int m = 0; m < 4; ++m) {
            #pragma unroll
            for (int jp = 0; jp < 2; ++jp) {
                const f32x2 a0 = {acc[m][0][jp * 2], acc[m][0][jp * 2 + 1]};
                const f32x2 a1 = {acc[m][1][jp * 2], acc[m][1][jp * 2 + 1]};
                const f32x2 xx = {xq[m][jp * 2], xq[m][jp * 2 + 1]};
                const f32x2 u0 = __builtin_elementwise_fma(mm2, a0, yy0);
                const f32x2 u1 = __builtin_elementwise_fma(mm2, a1, yy1);
                const f32x2 v0 = __builtin_elementwise_fma(mm2, a0, xx);
                const f32x2 v1 = __builtin_elementwise_fma(mm2, a1, xx);
                rowm[m][jp * 2]     = fminf(fminf(u0.x, u1.x), rowm[m][jp * 2]);
                rowm[m][jp * 2 + 1] = fminf(fminf(u0.y, u1.y), rowm[m][jp * 2 + 1]);
                colm0 = fminf(fminf(v0.x, v0.y), colm0);
                colm1 = fminf(fminf(v1.x, v1.y), colm1);
            }
        }
        // col-min across the 4 lh groups; store to LDS (wave-exclusive slots)
        colm0 = fminf(colm0, __shfl_xor(colm0, 16));
        colm0 = fminf(colm0, __shfl_xor(colm0, 32));
        colm1 = fminf(colm1, __shfl_xor(colm1, 16));
        colm1 = fminf(colm1, __shfl_xor(colm1, 32));
        if (lh == 0) {
            colbuf[ct * 128 + w * 32 + lr]      = colm0;
            colbuf[ct * 128 + w * 32 + lr + 16] = colm1;
        }
    }

    // ---- row-min: cross-lane (lr) reduce once per block, then cross-wave LDS
    #pragma unroll
    for (int m = 0; m < 4; ++m)
        #pragma unroll
        for (int j = 0; j < 4; ++j) {
            float v = rowm[m][j];
            v = fminf(v, __shfl_xor(v, 1));
            v = fminf(v, __shfl_xor(v, 2));
            v = fminf(v, __shfl_xor(v, 4));
            v = fminf(v, __shfl_xor(v, 8));
            if (lr == 0) {
                const int row = m * 16 + lh * 4 + j;
                const float d2 = fmaxf(ldsX[row] + v, 0.f);
                atomicMin(&lrow[row], __float_as_uint(d2));   // LDS atomic
            }
        }
    __syncthreads();

    // ---- flush: fire-and-forget global atomics AFTER the final barrier
    if (tid < 64) atomicMin(&rmin[brow + tid], lrow[tid]);
    {
        const f32x4 cv = *(const f32x4*)&colbuf[tid * 4];
        const float4 yq = *(const float4*)&y2[bcol0 + tid * 4];
        const float d0 = fmaxf(cv[0] + yq.x, 0.f);
        const float d1 = fmaxf(cv[1] + yq.y, 0.f);
        const float d2 = fmaxf(cv[2] + yq.z, 0.f);
        const float d3 = fmaxf(cv[3] + yq.w, 0.f);
        atomicMin(&cmin[bcol0 + tid * 4 + 0], __float_as_uint(d0));
        atomicMin(&cmin[bcol0 + tid * 4 + 1], __float_as_uint(d1));
        atomicMin(&cmin[bcol0 + tid * 4 + 2], __float_as_uint(d2));
        atomicMin(&cmin[bcol0 + tid * 4 + 3], __float_as_uint(d3));
    }
}

// ---------------------------------------------------------------------------
// finalize: out = mean(sqrt(rmin)) + mean(sqrt(cmin)); 1024 thr, uint4 loads.
// ---------------------------------------------------------------------------
__global__ __launch_bounds__(1024) void ahd_finalize(
    const unsigned int* __restrict__ rmin, const unsigned int* __restrict__ cmin,
    float* __restrict__ out, int N, int M)
{
    const int tid = threadIdx.x;
    const uint4* r4 = (const uint4*)rmin;
    const uint4* c4 = (const uint4*)cmin;
    float sa = 0.f, sb = 0.f;
    for (int i = tid; i < (N >> 2); i += 1024) {
        const uint4 v = r4[i];
        sa += sqrtf(__uint_as_float(v.x)) + sqrtf(__uint_as_float(v.y))
            + sqrtf(__uint_as_float(v.z)) + sqrtf(__uint_as_float(v.w));
    }
    for (int i = tid; i < (M >> 2); i += 1024) {
        const uint4 v = c4[i];
        sb += sqrtf(__uint_as_float(v.x)) + sqrtf(__uint_as_float(v.y))
            + sqrtf(__uint_as_float(v.z)) + sqrtf(__uint_as_float(v.w));
    }
    float v = sa / (float)N + sb / (float)M;
    #pragma unroll
    for (int s = 1; s < 64; s <<= 1) v += __shfl_xor(v, s);
    __shared__ float red[16];
    if ((tid & 63) == 0) red[tid >> 6] = v;
    __syncthreads();
    if (tid == 0) {
        float t = 0.f;
        #pragma unroll
        for (int i = 0; i < 16; ++i) t += red[i];
        out[0] = t;
    }
}

extern "C" void kernel_launch(void* const* d_in, const int* in_sizes, int n_in,
                              void* d_out, int out_size, void* d_ws, size_t ws_size,
                              hipStream_t stream) {
    const float* s1 = (const float*)d_in[0];
    const float* s2 = (const float*)d_in[1];
    const int N = in_sizes[0] / 64;
    const int M = in_sizes[1] / 64;

    char* ws = (char*)d_ws;
    __hip_bfloat16* abf = (__hip_bfloat16*)ws;
    __hip_bfloat16* bbf = (__hip_bfloat16*)(ws + (size_t)N * 128);
    float* x2 = (float*)(ws + (size_t)(N + M) * 128);
    float* y2 = x2 + N;
    unsigned int* rmin = (unsigned int*)(y2 + M);
    unsigned int* cmin = rmin + N;

    const int prows = ((N + M) * 16 + 255) / 256;   // 16 lanes per row
    ahd_prep<<<prows, 256, 0, stream>>>(s1, s2, abf, bbf, x2, y2,
                                        rmin, cmin, N, M);
    const int NRB = N / 64;             // 256 row-blocks
    const int STRIPS = M / 1024;        // 16 col-strips
    const int nwg = NRB * STRIPS;       // 4096 blocks
    ahd_gemm<<<nwg, 256, 0, stream>>>(abf, bbf, x2, y2, rmin, cmin, NRB, nwg);
    ahd_finalize<<<1, 1024, 0, stream>>>(rmin, cmin, (float*)d_out, N, M);
}

// Round 7
// 174.775 us; speedup vs baseline: 1.8118x; 1.8118x over previous
//
#include <hip/hip_runtime.h>
#include <hip/hip_bf16.h>

typedef __attribute__((ext_vector_type(8))) short short8;  // 8 bf16 (4 VGPRs)
typedef __attribute__((ext_vector_type(4))) short short4v;
typedef __attribute__((ext_vector_type(4))) float f32x4;

#define INF_BITS 0x7F800000u

// ---------------------------------------------------------------------------
// prep: fp32 -> bf16, exact fp32 row norms, init min arrays. 16 lanes per row,
// float4 loads / short4 (8B) stores.
// ---------------------------------------------------------------------------
__global__ __launch_bounds__(256) void ahd_prep(
    const float* __restrict__ s1, const float* __restrict__ s2,
    __hip_bfloat16* __restrict__ abf, __hip_bfloat16* __restrict__ bbf,
    float* __restrict__ x2, float* __restrict__ y2,
    unsigned int* __restrict__ rmin, unsigned int* __restrict__ cmin,
    int N, int M)
{
    const int t   = blockIdx.x * 256 + threadIdx.x;
    const int row = t >> 4;
    const int sub = t & 15;

    if (t < N)          rmin[t]     = INF_BITS;
    else if (t < N + M) cmin[t - N] = INF_BITS;

    const float* src; __hip_bfloat16* dst; float* nrm; int r;
    if (row < N)            { src = s1; dst = abf; nrm = x2; r = row; }
    else if (row < N + M)   { src = s2; dst = bbf; nrm = y2; r = row - N; }
    else return;

    const float4 v = *(const float4*)&src[(size_t)r * 64 + sub * 4];
    __hip_bfloat16 h0 = __float2bfloat16(v.x), h1 = __float2bfloat16(v.y);
    __hip_bfloat16 h2 = __float2bfloat16(v.z), h3 = __float2bfloat16(v.w);
    short4v sv = { *(short*)&h0, *(short*)&h1, *(short*)&h2, *(short*)&h3 };
    *(short4v*)&dst[(size_t)r * 64 + sub * 4] = sv;

    float ss = v.x * v.x + v.y * v.y + v.z * v.z + v.w * v.w;
    ss += __shfl_xor(ss, 1);
    ss += __shfl_xor(ss, 2);
    ss += __shfl_xor(ss, 4);
    ss += __shfl_xor(ss, 8);
    if (sub == 0) nrm[r] = ss;
}

// ---------------------------------------------------------------------------
// fused distance-GEMM + row/col min.
// Block: 128 rows x 1024-col strip, 4 waves. Wave w exclusively owns rows
// [w*32, w*32+32) x the whole strip: 32 col-tiles of 32 cols (2m x 2n frags
// of 16x16x32). Small live set (~110 VGPR) so the compiler NATURALLY lands
// <=128 -> 4 waves/SIMD (rounds 5/6 lesson: forcing __launch_bounds__(,3)
// causes catastrophic scratch spill; occupancy steps are 64/128/256).
// No barriers in the loop; B + y2 reg-prefetched depth 1 (R4-style, never
// spilled under plain bounds). Epilogue is scalar-only, 3 VALU/element:
// s = x2+y2; d2 = fma(-2,a,s); min3 trees for row/col mins. Rows flush
// straight to global atomics (wave-exclusive); cols via wave-private colbuf
// slices merged after the single final barrier.
// ---------------------------------------------------------------------------
__global__ __launch_bounds__(256) void ahd_gemm(
    const __hip_bfloat16* __restrict__ abf, const __hip_bfloat16* __restrict__ bbf,
    const float* __restrict__ x2, const float* __restrict__ y2,
    unsigned int* __restrict__ rmin, unsigned int* __restrict__ cmin,
    int NRB, int nwg)
{
    __shared__ __attribute__((aligned(128))) char ldsA[16384];
    __shared__ float colbuf[4][1024];

    const int tid  = threadIdx.x;
    const int lane = tid & 63;
    const int w    = tid >> 6;
    const int lr   = lane & 15, lh = lane >> 4;

    // XCD-bijective swizzle (nwg % 8 == 0)
    const int bid = blockIdx.x;
    const int swz = (bid & 7) * (nwg >> 3) + (bid >> 3);
    const int brow  = (swz % NRB) * 128;
    const int bcol0 = (swz / NRB) * 1024;

    // ---- stage A tile (16 KB) once; linear LDS dest, swizzled source
    const char* aT = (const char*)abf + (size_t)brow * 128;
    #pragma unroll
    for (int it = 0; it < 4; ++it) {
        const int dst = w * 1024 + it * 4096;
        const int o   = dst + lane * 16;
        const int so  = o ^ ((o >> 3) & 0x70);
        __builtin_amdgcn_global_load_lds(
            (const __attribute__((address_space(1))) void*)(aT + so),
            (__attribute__((address_space(3))) void*)(ldsA + dst), 16, 0, 0);
    }
    __syncthreads();   // drains A staging; the ONLY barrier before col flush

    // ---- A fragments (this wave's 32 rows) + x^2 in registers
    short8 afr[2][2];
    #pragma unroll
    for (int ks = 0; ks < 2; ++ks)
        #pragma unroll
        for (int m = 0; m < 2; ++m) {
            int o = (w * 32 + m * 16 + lr) * 128 + ks * 64 + lh * 16;
            o ^= (o >> 3) & 0x70;
            afr[ks][m] = *(const short8*)(ldsA + o);
        }
    f32x4 xq[2];
    #pragma unroll
    for (int m = 0; m < 2; ++m)
        xq[m] = *(const f32x4*)&x2[brow + w * 32 + m * 16 + lh * 4];

    float rowm[2][4];
    #pragma unroll
    for (int m = 0; m < 2; ++m)
        #pragma unroll
        for (int j = 0; j < 4; ++j) rowm[m][j] = 1e30f;

    // ---- B / y2 pointers; frag (n,ks) at bptr + n*2048 + ks*64, +4096/tile
    const char*  bptr = (const char*)bbf + (size_t)(bcol0 + lr) * 128 + lh * 16;
    const float* yptr = y2 + bcol0 + lr;

    short8 bcur[4];
    #pragma unroll
    for (int q = 0; q < 4; ++q)
        bcur[q] = *(const short8*)(bptr + (q >> 1) * 2048 + (q & 1) * 64);
    float yv0 = yptr[0];
    float yv1 = yptr[16];

    const f32x4 ZERO = {0.f, 0.f, 0.f, 0.f};

    #pragma unroll 2
    for (int ct = 0; ct < 32; ++ct) {
        // ---- prefetch next tile's B frags + y2 (depth 1)
        short8 bnxt[4];
        float yn0 = 0.f, yn1 = 0.f;
        if (ct < 31) {
            const char* bt = bptr + 4096;
            #pragma unroll
            for (int q = 0; q < 4; ++q)
                bnxt[q] = *(const short8*)(bt + (q >> 1) * 2048 + (q & 1) * 64);
            yn0 = yptr[32];
            yn1 = yptr[48];
        }

        // ---- MFMA: 2 ksteps x (2m x 2n), 4 independent depth-2 chains
        f32x4 acc[2][2];
        #pragma unroll
        for (int m = 0; m < 2; ++m)
            #pragma unroll
            for (int n = 0; n < 2; ++n)
                acc[m][n] = __builtin_amdgcn_mfma_f32_16x16x32_bf16(
                                afr[0][m], bcur[n * 2], ZERO, 0, 0, 0);
        #pragma unroll
        for (int m = 0; m < 2; ++m)
            #pragma unroll
            for (int n = 0; n < 2; ++n)
                acc[m][n] = __builtin_amdgcn_mfma_f32_16x16x32_bf16(
                                afr[1][m], bcur[n * 2 + 1], acc[m][n], 0, 0, 0);

        // ---- epilogue: 3 VALU/element (add, fma, shared min3)
        float colm0 = 1e30f, colm1 = 1e30f;
        #pragma unroll
        for (int m = 0; m < 2; ++m) {
            #pragma unroll
            for (int jp = 0; jp < 2; ++jp) {
                const int j0 = jp * 2, j1 = jp * 2 + 1;
                const float d00 = fmaf(-2.f, acc[m][0][j0], xq[m][j0] + yv0);
                const float d01 = fmaf(-2.f, acc[m][1][j0], xq[m][j0] + yv1);
                const float d10 = fmaf(-2.f, acc[m][0][j1], xq[m][j1] + yv0);
                const float d11 = fmaf(-2.f, acc[m][1][j1], xq[m][j1] + yv1);
                rowm[m][j0] = fminf(fminf(d00, d01), rowm[m][j0]);  // v_min3
                rowm[m][j1] = fminf(fminf(d10, d11), rowm[m][j1]);
                colm0 = fminf(fminf(d00, d10), colm0);
                colm1 = fminf(fminf(d01, d11), colm1);
            }
        }
        // col partial: reduce over the 4 lh groups, park in wave-private LDS
        colm0 = fminf(colm0, __shfl_xor(colm0, 16));
        colm0 = fminf(colm0, __shfl_xor(colm0, 32));
        colm1 = fminf(colm1, __shfl_xor(colm1, 16));
        colm1 = fminf(colm1, __shfl_xor(colm1, 32));
        if (lh == 0) {
            colbuf[w][ct * 32 + lr]      = colm0;
            colbuf[w][ct * 32 + 16 + lr] = colm1;
        }

        // ---- rotate pipeline
        if (ct < 31) {
            #pragma unroll
            for (int q = 0; q < 4; ++q) bcur[q] = bnxt[q];
            yv0 = yn0; yv1 = yn1;
            bptr += 4096;
            yptr += 32;
        }
    }

    // ---- row flush: wave-exclusive rows -> straight to global atomics
    #pragma unroll
    for (int m = 0; m < 2; ++m)
        #pragma unroll
        for (int j = 0; j < 4; ++j) {
            float v = rowm[m][j];
            v = fminf(v, __shfl_xor(v, 1));
            v = fminf(v, __shfl_xor(v, 2));
            v = fminf(v, __shfl_xor(v, 4));
            v = fminf(v, __shfl_xor(v, 8));
            if (lr == 0) {
                const int row = brow + w * 32 + m * 16 + lh * 4 + j;
                atomicMin(&rmin[row], __float_as_uint(fmaxf(v, 0.f)));
            }
        }

    __syncthreads();

    // ---- col flush: merge the 4 wave slices; fire-and-forget atomics
    {
        const int c = tid * 4;
        const f32x4 c0 = *(const f32x4*)&colbuf[0][c];
        const f32x4 c1 = *(const f32x4*)&colbuf[1][c];
        const f32x4 c2 = *(const f32x4*)&colbuf[2][c];
        const f32x4 c3 = *(const f32x4*)&colbuf[3][c];
        #pragma unroll
        for (int k = 0; k < 4; ++k) {
            const float v = fminf(fminf(c0[k], c1[k]), fminf(c2[k], c3[k]));
            atomicMin(&cmin[bcol0 + c + k], __float_as_uint(fmaxf(v, 0.f)));
        }
    }
}

// ---------------------------------------------------------------------------
// finalize: out = mean(sqrt(rmin)) + mean(sqrt(cmin)); 1024 thr, uint4 loads.
// ---------------------------------------------------------------------------
__global__ __launch_bounds__(1024) void ahd_finalize(
    const unsigned int* __restrict__ rmin, const unsigned int* __restrict__ cmin,
    float* __restrict__ out, int N, int M)
{
    const int tid = threadIdx.x;
    const uint4* r4 = (const uint4*)rmin;
    const uint4* c4 = (const uint4*)cmin;
    float sa = 0.f, sb = 0.f;
    for (int i = tid; i < (N >> 2); i += 1024) {
        const uint4 v = r4[i];
        sa += sqrtf(__uint_as_float(v.x)) + sqrtf(__uint_as_float(v.y))
            + sqrtf(__uint_as_float(v.z)) + sqrtf(__uint_as_float(v.w));
    }
    for (int i = tid; i < (M >> 2); i += 1024) {
        const uint4 v = c4[i];
        sb += sqrtf(__uint_as_float(v.x)) + sqrtf(__uint_as_float(v.y))
            + sqrtf(__uint_as_float(v.z)) + sqrtf(__uint_as_float(v.w));
    }
    float v = sa / (float)N + sb / (float)M;
    #pragma unroll
    for (int s = 1; s < 64; s <<= 1) v += __shfl_xor(v, s);
    __shared__ float red[16];
    if ((tid & 63) == 0) red[tid >> 6] = v;
    __syncthreads();
    if (tid == 0) {
        float t = 0.f;
        #pragma unroll
        for (int i = 0; i < 16; ++i) t += red[i];
        out[0] = t;
    }
}

extern "C" void kernel_launch(void* const* d_in, const int* in_sizes, int n_in,
                              void* d_out, int out_size, void* d_ws, size_t ws_size,
                              hipStream_t stream) {
    const float* s1 = (const float*)d_in[0];
    const float* s2 = (const float*)d_in[1];
    const int N = in_sizes[0] / 64;
    const int M = in_sizes[1] / 64;

    char* ws = (char*)d_ws;
    __hip_bfloat16* abf = (__hip_bfloat16*)ws;
    __hip_bfloat16* bbf = (__hip_bfloat16*)(ws + (size_t)N * 128);
    float* x2 = (float*)(ws + (size_t)(N + M) * 128);
    float* y2 = x2 + N;
    unsigned int* rmin = (unsigned int*)(y2 + M);
    unsigned int* cmin = rmin + N;

    const int prows = ((N + M) * 16 + 255) / 256;   // 16 lanes per row
    ahd_prep<<<prows, 256, 0, stream>>>(s1, s2, abf, bbf, x2, y2,
                                        rmin, cmin, N, M);
    const int NRB = N / 128;            // 128 row-blocks
    const int STRIPS = M / 1024;        // 16 col-strips
    const int nwg = NRB * STRIPS;       // 2048 blocks
    ahd_gemm<<<nwg, 256, 0, stream>>>(abf, bbf, x2, y2, rmin, cmin, NRB, nwg);
    ahd_finalize<<<1, 1024, 0, stream>>>(rmin, cmin, (float*)d_out, N, M);
}

// Round 8
// 154.915 us; speedup vs baseline: 2.0441x; 1.1282x over previous
//
#include <hip/hip_runtime.h>
#include <hip/hip_bf16.h>

typedef __attribute__((ext_vector_type(8))) short short8;  // 8 bf16 (4 VGPRs)
typedef __attribute__((ext_vector_type(4))) short short4v;
typedef __attribute__((ext_vector_type(4))) float f32x4;
typedef __attribute__((ext_vector_type(2))) float f32x2;

#define INF_BITS 0x7F800000u

// ---------------------------------------------------------------------------
// prep: fp32 -> bf16, exact fp32 row norms, init min arrays. 16 lanes per row,
// float4 loads / short4 (8B) stores.
// ---------------------------------------------------------------------------
__global__ __launch_bounds__(256) void ahd_prep(
    const float* __restrict__ s1, const float* __restrict__ s2,
    __hip_bfloat16* __restrict__ abf, __hip_bfloat16* __restrict__ bbf,
    float* __restrict__ x2, float* __restrict__ y2,
    unsigned int* __restrict__ rmin, unsigned int* __restrict__ cmin,
    int N, int M)
{
    const int t   = blockIdx.x * 256 + threadIdx.x;
    const int row = t >> 4;
    const int sub = t & 15;

    if (t < N)          rmin[t]     = INF_BITS;
    else if (t < N + M) cmin[t - N] = INF_BITS;

    const float* src; __hip_bfloat16* dst; float* nrm; int r;
    if (row < N)            { src = s1; dst = abf; nrm = x2; r = row; }
    else if (row < N + M)   { src = s2; dst = bbf; nrm = y2; r = row - N; }
    else return;

    const float4 v = *(const float4*)&src[(size_t)r * 64 + sub * 4];
    __hip_bfloat16 h0 = __float2bfloat16(v.x), h1 = __float2bfloat16(v.y);
    __hip_bfloat16 h2 = __float2bfloat16(v.z), h3 = __float2bfloat16(v.w);
    short4v sv = { *(short*)&h0, *(short*)&h1, *(short*)&h2, *(short*)&h3 };
    *(short4v*)&dst[(size_t)r * 64 + sub * 4] = sv;

    float ss = v.x * v.x + v.y * v.y + v.z * v.z + v.w * v.w;
    ss += __shfl_xor(ss, 1);
    ss += __shfl_xor(ss, 2);
    ss += __shfl_xor(ss, 4);
    ss += __shfl_xor(ss, 8);
    if (sub == 0) nrm[r] = ss;
}

// ---------------------------------------------------------------------------
// fused distance-GEMM + row/col min. R1 skeleton (proven fastest), leaned out:
// Block: 128x128 output tile, K=64 single pass, 4 waves in 4x1 -- wave w owns
// rows [w*32, w*32+32) x all 128 cols. Rows are WAVE-EXCLUSIVE: row mins
// flush straight to global atomics (no LDS merge, no final barrier). The
// n-dimension is STREAMED: per 16-col frag, 4 MFMAs into a transient 8-reg
// acc, epilogue fused immediately (acc never materializes as 64 regs;
// unrolled loop lets MFMA(n+1) overlap epilogue(n) on separate pipes).
// Live set ~90 VGPR, LDS exactly 32 KB -> 5 blocks/CU. One prologue barrier.
// Epilogue: 3 pk-ops/2 elements on adjacent acc pairs. All atomics
// fire-and-forget at wave end.
// ---------------------------------------------------------------------------
__global__ __launch_bounds__(256) void ahd_gemm(
    const __hip_bfloat16* __restrict__ abf, const __hip_bfloat16* __restrict__ bbf,
    const float* __restrict__ x2, const float* __restrict__ y2,
    unsigned int* __restrict__ rmin, unsigned int* __restrict__ cmin)
{
    __shared__ __attribute__((aligned(128))) char ldsA[16384];
    __shared__ __attribute__((aligned(128))) char ldsB[16384];

    const int tid  = threadIdx.x;
    const int lane = tid & 63;
    const int w    = tid >> 6;
    const int lr   = lane & 15, lh = lane >> 4;

    const int brow = blockIdx.x * 128;
    const int bcol = blockIdx.y * 128;

    // ---- stage A: wave-own rows (wave w stages and reads rows w*32..+32)
    const char* aT = (const char*)abf + (size_t)brow * 128;
    #pragma unroll
    for (int it = 0; it < 4; ++it) {
        const int dst = w * 4096 + it * 1024;
        const int o   = dst + lane * 16;
        const int so  = o ^ ((o >> 3) & 0x70);
        __builtin_amdgcn_global_load_lds(
            (const __attribute__((address_space(1))) void*)(aT + so),
            (__attribute__((address_space(3))) void*)(ldsA + dst), 16, 0, 0);
    }
    // ---- stage B cooperatively (all waves read all of it)
    const char* bT = (const char*)bbf + (size_t)bcol * 128;
    #pragma unroll
    for (int it = 0; it < 4; ++it) {
        const int dst = w * 1024 + it * 4096;
        const int o   = dst + lane * 16;
        const int so  = o ^ ((o >> 3) & 0x70);
        __builtin_amdgcn_global_load_lds(
            (const __attribute__((address_space(1))) void*)(bT + so),
            (__attribute__((address_space(3))) void*)(ldsB + dst), 16, 0, 0);
    }

    // ---- x^2 / y^2 into registers (global loads, independent of staging)
    f32x2 xq[2][2];   // [m][jp]
    #pragma unroll
    for (int m = 0; m < 2; ++m) {
        const f32x4 xv = *(const f32x4*)&x2[brow + w * 32 + m * 16 + lh * 4];
        xq[m][0] = (f32x2){xv[0], xv[1]};
        xq[m][1] = (f32x2){xv[2], xv[3]};
    }
    float yv[8];
    #pragma unroll
    for (int n = 0; n < 8; ++n)
        yv[n] = y2[bcol + n * 16 + lr];

    __syncthreads();   // drains staging; the ONLY barrier

    // ---- A fragments for this wave's 32 rows: [ks][m]
    short8 afr[2][2];
    #pragma unroll
    for (int ks = 0; ks < 2; ++ks)
        #pragma unroll
        for (int m = 0; m < 2; ++m) {
            int o = (w * 32 + m * 16 + lr) * 128 + ks * 64 + lh * 16;
            o ^= (o >> 3) & 0x70;
            afr[ks][m] = *(const short8*)(ldsA + o);
        }

    const f32x4 ZERO = {0.f, 0.f, 0.f, 0.f};
    const f32x2 mm2  = {-2.f, -2.f};

    f32x2 rowm[2][2];
    #pragma unroll
    for (int m = 0; m < 2; ++m)
        #pragma unroll
        for (int jp = 0; jp < 2; ++jp) rowm[m][jp] = (f32x2){1e30f, 1e30f};
    f32x2 colm2[8];

    // ---- streamed n-loop: 8 x {2 ds_read, 4 MFMA, fused 15-pk epilogue}
    #pragma unroll
    for (int n = 0; n < 8; ++n) {
        const int ob = (n * 16 + lr) * 128 + lh * 16;
        const int o0 = ob ^ ((ob >> 3) & 0x70);
        const int o1 = (ob + 64) ^ (((ob + 64) >> 3) & 0x70);
        const short8 b0 = *(const short8*)(ldsB + o0);
        const short8 b1 = *(const short8*)(ldsB + o1);

        f32x4 a0 = __builtin_amdgcn_mfma_f32_16x16x32_bf16(afr[0][0], b0, ZERO, 0, 0, 0);
        f32x4 a1 = __builtin_amdgcn_mfma_f32_16x16x32_bf16(afr[0][1], b0, ZERO, 0, 0, 0);
        a0 = __builtin_amdgcn_mfma_f32_16x16x32_bf16(afr[1][0], b1, a0, 0, 0, 0);
        a1 = __builtin_amdgcn_mfma_f32_16x16x32_bf16(afr[1][1], b1, a1, 0, 0, 0);

        const f32x2 yy = {yv[n], yv[n]};
        // m=0
        const f32x2 d00 = __builtin_elementwise_fma(mm2, (f32x2){a0[0], a0[1]}, xq[0][0] + yy);
        const f32x2 d01 = __builtin_elementwise_fma(mm2, (f32x2){a0[2], a0[3]}, xq[0][1] + yy);
        rowm[0][0] = __builtin_elementwise_min(rowm[0][0], d00);
        rowm[0][1] = __builtin_elementwise_min(rowm[0][1], d01);
        // m=1
        const f32x2 d10 = __builtin_elementwise_fma(mm2, (f32x2){a1[0], a1[1]}, xq[1][0] + yy);
        const f32x2 d11 = __builtin_elementwise_fma(mm2, (f32x2){a1[2], a1[3]}, xq[1][1] + yy);
        rowm[1][0] = __builtin_elementwise_min(rowm[1][0], d10);
        rowm[1][1] = __builtin_elementwise_min(rowm[1][1], d11);
        // col partial (this n only)
        colm2[n] = __builtin_elementwise_min(
                       __builtin_elementwise_min(d00, d01),
                       __builtin_elementwise_min(d10, d11));
    }

    // ---- row flush: wave-exclusive rows -> shfl over 16 lanes, global atomic
    #pragma unroll
    for (int m = 0; m < 2; ++m)
        #pragma unroll
        for (int jp = 0; jp < 2; ++jp)
            #pragma unroll
            for (int c = 0; c < 2; ++c) {
                float v = rowm[m][jp][c];
                v = fminf(v, __shfl_xor(v, 1));
                v = fminf(v, __shfl_xor(v, 2));
                v = fminf(v, __shfl_xor(v, 4));
                v = fminf(v, __shfl_xor(v, 8));
                if (lr == 0) {
                    const int row = brow + w * 32 + m * 16 + lh * 4 + jp * 2 + c;
                    atomicMin(&rmin[row], __float_as_uint(fmaxf(v, 0.f)));
                }
            }

    // ---- col flush: combine pair, shfl across lh groups, global atomic
    #pragma unroll
    for (int n = 0; n < 8; ++n) {
        float c = fminf(colm2[n][0], colm2[n][1]);
        c = fminf(c, __shfl_xor(c, 16));
        c = fminf(c, __shfl_xor(c, 32));
        if (lh == 0)
            atomicMin(&cmin[bcol + n * 16 + lr], __float_as_uint(fmaxf(c, 0.f)));
    }
}

// ---------------------------------------------------------------------------
// finalize: out = mean(sqrt(rmin)) + mean(sqrt(cmin)); 1024 thr, uint4 loads.
// ---------------------------------------------------------------------------
__global__ __launch_bounds__(1024) void ahd_finalize(
    const unsigned int* __restrict__ rmin, const unsigned int* __restrict__ cmin,
    float* __restrict__ out, int N, int M)
{
    const int tid = threadIdx.x;
    const uint4* r4 = (const uint4*)rmin;
    const uint4* c4 = (const uint4*)cmin;
    float sa = 0.f, sb = 0.f;
    for (int i = tid; i < (N >> 2); i += 1024) {
        const uint4 v = r4[i];
        sa += sqrtf(__uint_as_float(v.x)) + sqrtf(__uint_as_float(v.y))
            + sqrtf(__uint_as_float(v.z)) + sqrtf(__uint_as_float(v.w));
    }
    for (int i = tid; i < (M >> 2); i += 1024) {
        const uint4 v = c4[i];
        sb += sqrtf(__uint_as_float(v.x)) + sqrtf(__uint_as_float(v.y))
            + sqrtf(__uint_as_float(v.z)) + sqrtf(__uint_as_float(v.w));
    }
    float v = sa / (float)N + sb / (float)M;
    #pragma unroll
    for (int s = 1; s < 64; s <<= 1) v += __shfl_xor(v, s);
    __shared__ float red[16];
    if ((tid & 63) == 0) red[tid >> 6] = v;
    __syncthreads();
    if (tid == 0) {
        float t = 0.f;
        #pragma unroll
        for (int i = 0; i < 16; ++i) t += red[i];
        out[0] = t;
    }
}

extern "C" void kernel_launch(void* const* d_in, const int* in_sizes, int n_in,
                              void* d_out, int out_size, void* d_ws, size_t ws_size,
                              hipStream_t stream) {
    const float* s1 = (const float*)d_in[0];
    const float* s2 = (const float*)d_in[1];
    const int N = in_sizes[0] / 64;
    const int M = in_sizes[1] / 64;

    char* ws = (char*)d_ws;
    __hip_bfloat16* abf = (__hip_bfloat16*)ws;
    __hip_bfloat16* bbf = (__hip_bfloat16*)(ws + (size_t)N * 128);
    float* x2 = (float*)(ws + (size_t)(N + M) * 128);
    float* y2 = x2 + N;
    unsigned int* rmin = (unsigned int*)(y2 + M);
    unsigned int* cmin = rmin + N;

    const int prows = ((N + M) * 16 + 255) / 256;   // 16 lanes per row
    ahd_prep<<<prows, 256, 0, stream>>>(s1, s2, abf, bbf, x2, y2,
                                        rmin, cmin, N, M);
    dim3 grid(N / 128, M / 128);                    // 16384 blocks
    ahd_gemm<<<grid, 256, 0, stream>>>(abf, bbf, x2, y2, rmin, cmin);
    ahd_finalize<<<1, 1024, 0, stream>>>(rmin, cmin, (float*)d_out, N, M);
}